// Round 1
// baseline (151.318 us; speedup 1.0000x reference)
//
#include <hip/hip_runtime.h>

// Problem constants: B=8, C=64, L=32, H=64, W=64
#define BB 8
#define CC 64
#define NSP 131072           // L*H*W = 32*64*64 = 1<<17
#define N4 32768             // NSP/4 float4s per (b,c) = 1<<15
#define CHUNKS 128           // per-b chunks in k1 (N4 / 256 threads)

// Kernel 1: for each spatial float4 chunk, loop channels once.
// Produces: g[b,n] = sum_c inpt[b,c,n]*g_w[c] (optional, to ws)
//           block partial sums of t[b,n] = sum_c inpt[b,c,n]*theta_w[c]
__global__ __launch_bounds__(256) void k1_gpart(
    const float* __restrict__ inpt, const float* __restrict__ theta_w,
    const float* __restrict__ g_w, float* __restrict__ g_out,
    float* __restrict__ partials, int write_g)
{
    int blk = blockIdx.x;                     // 0 .. B*CHUNKS-1 (1024)
    int b = blk >> 7;
    int n4 = ((blk & 127) << 8) + threadIdx.x;  // float4 index within N4
    const float4* base = reinterpret_cast<const float4*>(inpt)
                         + (((size_t)b) << 21) + n4;   // b*C*N4

    float4 t4 = make_float4(0.f, 0.f, 0.f, 0.f);
    float4 g4 = make_float4(0.f, 0.f, 0.f, 0.f);
    #pragma unroll 8
    for (int c = 0; c < CC; ++c) {
        float4 x = base[((size_t)c) << 15];   // channel stride N4
        float tw = theta_w[c];
        float gw = g_w[c];
        t4.x = fmaf(x.x, tw, t4.x); t4.y = fmaf(x.y, tw, t4.y);
        t4.z = fmaf(x.z, tw, t4.z); t4.w = fmaf(x.w, tw, t4.w);
        g4.x = fmaf(x.x, gw, g4.x); g4.y = fmaf(x.y, gw, g4.y);
        g4.z = fmaf(x.z, gw, g4.z); g4.w = fmaf(x.w, gw, g4.w);
    }
    if (write_g)
        reinterpret_cast<float4*>(g_out)[(((size_t)b) << 15) + n4] = g4;

    // block-reduce t (deterministic: shuffle tree + fixed-order LDS combine)
    float t = (t4.x + t4.y) + (t4.z + t4.w);
    #pragma unroll
    for (int off = 32; off > 0; off >>= 1) t += __shfl_down(t, off);
    __shared__ float red[4];
    int wid = threadIdx.x >> 6;
    if ((threadIdx.x & 63) == 0) red[wid] = t;
    __syncthreads();
    if (threadIdx.x == 0) partials[blk] = (red[0] + red[1]) + (red[2] + red[3]);
}

// Kernel 2: reduce 128 partials per batch -> mt[b] (8 waves, one per b)
__global__ __launch_bounds__(512) void k2_mt(
    const float* __restrict__ partials, float* __restrict__ mt)
{
    int b = threadIdx.x >> 6;
    int lane = threadIdx.x & 63;
    float v = partials[(b << 7) + lane] + partials[(b << 7) + 64 + lane];
    #pragma unroll
    for (int off = 32; off > 0; off >>= 1) v += __shfl_down(v, off);
    if (lane == 0) mt[b] = v * (1.0f / (float)NSP);
}

// Kernel 3 (primary): pure float4 stream, out = inpt + g*(mt[b]*h_w[c]) + h_b[c]
__global__ __launch_bounds__(256) void k3_stream(
    const float* __restrict__ inpt, const float* __restrict__ g,
    const float* __restrict__ mt, const float* __restrict__ h_w,
    const float* __restrict__ h_b, float* __restrict__ out)
{
    size_t i4 = (size_t)blockIdx.x * 256 + threadIdx.x;  // over B*C*N4
    int bc = (int)(i4 >> 15);
    int b = bc >> 6, c = bc & 63;
    float4 x  = reinterpret_cast<const float4*>(inpt)[i4];
    float4 gv = reinterpret_cast<const float4*>(g)[(((size_t)b) << 15) + (i4 & 32767)];
    float s  = mt[b] * h_w[c];
    float hb = h_b[c];
    float4 o;
    o.x = fmaf(gv.x, s, x.x + hb);
    o.y = fmaf(gv.y, s, x.y + hb);
    o.z = fmaf(gv.z, s, x.z + hb);
    o.w = fmaf(gv.w, s, x.w + hb);
    reinterpret_cast<float4*>(out)[i4] = o;
}

// Kernel 3 (fallback, tiny ws): register-cache 64 channels per spatial pos,
// recompute g inline. Scalar (dword) loads, coalesced across lanes.
__global__ __launch_bounds__(256) void k3_reg(
    const float* __restrict__ inpt, const float* __restrict__ g_w,
    const float* __restrict__ mt, const float* __restrict__ h_w,
    const float* __restrict__ h_b, float* __restrict__ out)
{
    size_t idx = (size_t)blockIdx.x * 256 + threadIdx.x;  // over B*NSP
    int b = (int)(idx >> 17);
    size_t n = idx & (NSP - 1);
    const float* base = inpt + (((size_t)b) * CC) * NSP + n;
    float vals[CC];
    float gacc = 0.f;
    #pragma unroll
    for (int c = 0; c < CC; ++c) {
        vals[c] = base[((size_t)c) << 17];
        gacc = fmaf(vals[c], g_w[c], gacc);
    }
    float s = gacc * mt[b];
    float* obase = out + (((size_t)b) * CC) * NSP + n;
    #pragma unroll
    for (int c = 0; c < CC; ++c)
        obase[((size_t)c) << 17] = fmaf(s, h_w[c], vals[c] + h_b[c]);
}

extern "C" void kernel_launch(void* const* d_in, const int* in_sizes, int n_in,
                              void* d_out, int out_size, void* d_ws, size_t ws_size,
                              hipStream_t stream)
{
    const float* inpt    = (const float*)d_in[0];
    const float* theta_w = (const float*)d_in[1];
    const float* g_w     = (const float*)d_in[2];
    const float* h_w     = (const float*)d_in[3];
    const float* h_b     = (const float*)d_in[4];
    float* out = (float*)d_out;

    const size_t g_bytes   = (size_t)BB * NSP * sizeof(float);  // 4 MiB
    const size_t need_full = g_bytes + 8192;
    char* ws = (char*)d_ws;

    if (ws_size >= need_full) {
        float* g        = (float*)ws;
        float* partials = (float*)(ws + g_bytes);
        float* mt       = (float*)(ws + g_bytes + 4096);
        hipLaunchKernelGGL(k1_gpart, dim3(BB * CHUNKS), dim3(256), 0, stream,
                           inpt, theta_w, g_w, g, partials, 1);
        hipLaunchKernelGGL(k2_mt, dim3(1), dim3(512), 0, stream, partials, mt);
        hipLaunchKernelGGL(k3_stream, dim3((BB * CC * N4) / 256), dim3(256), 0, stream,
                           inpt, g, mt, h_w, h_b, out);
    } else {
        float* partials = (float*)ws;
        float* mt       = (float*)(ws + 4096);
        hipLaunchKernelGGL(k1_gpart, dim3(BB * CHUNKS), dim3(256), 0, stream,
                           inpt, theta_w, g_w, nullptr, partials, 0);
        hipLaunchKernelGGL(k2_mt, dim3(1), dim3(512), 0, stream, partials, mt);
        hipLaunchKernelGGL(k3_reg, dim3((BB * NSP) / 256), dim3(256), 0, stream,
                           inpt, g_w, mt, h_w, h_b, out);
    }
}

// Round 2
// 128.812 us; speedup vs baseline: 1.1747x; 1.1747x over previous
//
#include <hip/hip_runtime.h>

// Problem constants: B=8, C=64, L=32, H=64, W=64
#define BB 8
#define CC 64
#define NSP 131072           // L*H*W = 1<<17 spatial positions per (b,c)
#define N4 32768             // NSP/4 float4s per (b,c)
#define QPB 8                // k1 sub-blocks per (b,c)
#define NPART (BB * CC * QPB)  // 4096 partials

// ---------------------------------------------------------------------------
// k1: pure contiguous streaming sum. Block (b*64+c)*8+q reduces a 16 KiB
// float4 span of channel (b,c). Deterministic tree reduction.
// mt[b] = sum_c theta_w[c] * (sum_n x[b,c,n]) / NSP  -- t[b,n] never formed.
// ---------------------------------------------------------------------------
__global__ __launch_bounds__(256) void k1_sum(
    const float* __restrict__ inpt, float* __restrict__ partials)
{
    int blk = blockIdx.x;                 // 0 .. NPART-1
    int bc = blk >> 3, q = blk & 7;
    const float4* base = reinterpret_cast<const float4*>(inpt)
                         + (((size_t)bc) << 15) + (q << 12);   // 4096 float4 span
    float4 s4 = make_float4(0.f, 0.f, 0.f, 0.f);
    #pragma unroll
    for (int i = 0; i < 16; ++i) {
        float4 x = base[i * 256 + threadIdx.x];
        s4.x += x.x; s4.y += x.y; s4.z += x.z; s4.w += x.w;
    }
    float s = (s4.x + s4.y) + (s4.z + s4.w);
    #pragma unroll
    for (int off = 32; off > 0; off >>= 1) s += __shfl_down(s, off);
    __shared__ float red[4];
    int wid = threadIdx.x >> 6;
    if ((threadIdx.x & 63) == 0) red[wid] = s;
    __syncthreads();
    if (threadIdx.x == 0) partials[blk] = (red[0] + red[1]) + (red[2] + red[3]);
}

// ---------------------------------------------------------------------------
// k2: 8 waves, one per batch. Lane c: sum its 8 partials, scale by theta_w[c],
// wave-reduce over the 64 channels -> mt[b].
// ---------------------------------------------------------------------------
__global__ __launch_bounds__(512) void k2_mt(
    const float* __restrict__ partials, const float* __restrict__ theta_w,
    float* __restrict__ mt)
{
    int b = threadIdx.x >> 6;
    int c = threadIdx.x & 63;
    const float* p = partials + (((b << 6) | c) << 3);
    float v = ((p[0] + p[1]) + (p[2] + p[3])) + ((p[4] + p[5]) + (p[6] + p[7]));
    v *= theta_w[c];
    #pragma unroll
    for (int off = 32; off > 0; off >>= 1) v += __shfl_down(v, off);
    if (c == 0) mt[b] = v * (1.0f / (float)NSP);
}

// ---------------------------------------------------------------------------
// k3: one thread per spatial position. Register-cache all 64 channel values
// (64 coalesced dword loads, 256B/wave segments), compute g inline, write
// out = x + (g*mt[b])*h_w[c] + h_b[c] with nontemporal stores.
// ---------------------------------------------------------------------------
__global__ __launch_bounds__(256) void k3_fused(
    const float* __restrict__ inpt, const float* __restrict__ g_w,
    const float* __restrict__ mt, const float* __restrict__ h_w,
    const float* __restrict__ h_b, float* __restrict__ out)
{
    size_t idx = (size_t)blockIdx.x * 256 + threadIdx.x;  // over B*NSP
    int b = (int)(idx >> 17);
    size_t n = idx & (NSP - 1);
    const float* base = inpt + ((((size_t)b) << 6) << 17) + n;

    float vals[CC];
    float gacc = 0.f;
    #pragma unroll
    for (int c = 0; c < CC; ++c) {
        vals[c] = base[((size_t)c) << 17];
        gacc = fmaf(vals[c], g_w[c], gacc);
    }
    float s = gacc * mt[b];
    float* obase = out + ((((size_t)b) << 6) << 17) + n;
    #pragma unroll
    for (int c = 0; c < CC; ++c) {
        float o = fmaf(s, h_w[c], vals[c] + h_b[c]);
        __builtin_nontemporal_store(o, obase + (((size_t)c) << 17));
    }
}

extern "C" void kernel_launch(void* const* d_in, const int* in_sizes, int n_in,
                              void* d_out, int out_size, void* d_ws, size_t ws_size,
                              hipStream_t stream)
{
    const float* inpt    = (const float*)d_in[0];
    const float* theta_w = (const float*)d_in[1];
    const float* g_w     = (const float*)d_in[2];
    const float* h_w     = (const float*)d_in[3];
    const float* h_b     = (const float*)d_in[4];
    float* out = (float*)d_out;

    char* ws = (char*)d_ws;
    float* partials = (float*)ws;                       // 4096 floats
    float* mt       = (float*)(ws + NPART * sizeof(float));  // 8 floats

    hipLaunchKernelGGL(k1_sum, dim3(NPART), dim3(256), 0, stream,
                       inpt, partials);
    hipLaunchKernelGGL(k2_mt, dim3(1), dim3(512), 0, stream,
                       partials, theta_w, mt);
    hipLaunchKernelGGL(k3_fused, dim3((BB * NSP) / 256), dim3(256), 0, stream,
                       inpt, g_w, mt, h_w, h_b, out);
}

// Round 3
// 127.553 us; speedup vs baseline: 1.1863x; 1.0099x over previous
//
#include <hip/hip_runtime.h>

// Problem constants: B=8, C=64, L=32, H=64, W=64
#define BB 8
#define CC 64
#define NSP 131072           // L*H*W = 1<<17 spatial positions per (b,c)
#define QPB 8                // k1 sub-blocks per (b,c)
#define NPART (BB * CC * QPB)  // 4096 partials

// ---------------------------------------------------------------------------
// k1: pure contiguous streaming sum (regular loads -> allocate in L2/L3).
// Block (b*64+c)*8+q reduces a 64 KiB span of channel (b,c).
// mt[b] = sum_c theta_w[c] * (sum_n x[b,c,n]) / NSP  -- t[b,n] never formed.
// ---------------------------------------------------------------------------
__global__ __launch_bounds__(256) void k1_sum(
    const float* __restrict__ inpt, float* __restrict__ partials)
{
    int blk = blockIdx.x;                 // 0 .. NPART-1
    int bc = blk >> 3, q = blk & 7;
    const float4* base = reinterpret_cast<const float4*>(inpt)
                         + (((size_t)bc) << 15) + (q << 12);   // 4096-float4 span
    float4 s4 = make_float4(0.f, 0.f, 0.f, 0.f);
    #pragma unroll
    for (int i = 0; i < 16; ++i) {
        float4 x = base[i * 256 + threadIdx.x];
        s4.x += x.x; s4.y += x.y; s4.z += x.z; s4.w += x.w;
    }
    float s = (s4.x + s4.y) + (s4.z + s4.w);
    #pragma unroll
    for (int off = 32; off > 0; off >>= 1) s += __shfl_down(s, off);
    __shared__ float red[4];
    int wid = threadIdx.x >> 6;
    if ((threadIdx.x & 63) == 0) red[wid] = s;
    __syncthreads();
    if (threadIdx.x == 0) partials[blk] = (red[0] + red[1]) + (red[2] + red[3]);
}

// ---------------------------------------------------------------------------
// k2: 8 waves, one per batch. Lane c: sum its 8 partials, scale by theta_w[c],
// wave-reduce over the 64 channels -> mt[b].
// ---------------------------------------------------------------------------
__global__ __launch_bounds__(512) void k2_mt(
    const float* __restrict__ partials, const float* __restrict__ theta_w,
    float* __restrict__ mt)
{
    int b = threadIdx.x >> 6;
    int c = threadIdx.x & 63;
    const float* p = partials + (((b << 6) | c) << 3);
    float v = ((p[0] + p[1]) + (p[2] + p[3])) + ((p[4] + p[5]) + (p[6] + p[7]));
    v *= theta_w[c];
    #pragma unroll
    for (int off = 32; off > 0; off >>= 1) v += __shfl_down(v, off);
    if (c == 0) mt[b] = v * (1.0f / (float)NSP);
}

// ---------------------------------------------------------------------------
// k3: one thread per spatial position, REVERSE block order (consume the MRU
// tail of k1's stream first -> maximize L3 hits on the input re-read).
// Register-cache all 64 channel values, compute g inline, write
// out = x + (g*mt[b])*h_w[c] + h_b[c] with nontemporal stores.
// ---------------------------------------------------------------------------
__global__ __launch_bounds__(256) void k3_fused(
    const float* __restrict__ inpt, const float* __restrict__ g_w,
    const float* __restrict__ mt, const float* __restrict__ h_w,
    const float* __restrict__ h_b, float* __restrict__ out)
{
    int rblk = (int)gridDim.x - 1 - (int)blockIdx.x;      // reverse order
    size_t idx = (size_t)rblk * 256 + threadIdx.x;        // over B*NSP
    int b = (int)(idx >> 17);
    size_t n = idx & (NSP - 1);
    const float* base = inpt + ((((size_t)b) << 6) << 17) + n;

    float vals[CC];
    float gacc = 0.f;
    #pragma unroll
    for (int c = 0; c < CC; ++c) {
        vals[c] = base[((size_t)c) << 17];
        gacc = fmaf(vals[c], g_w[c], gacc);
    }
    float s = gacc * mt[b];
    float* obase = out + ((((size_t)b) << 6) << 17) + n;
    #pragma unroll
    for (int c = 0; c < CC; ++c) {
        float o = fmaf(s, h_w[c], vals[c] + h_b[c]);
        __builtin_nontemporal_store(o, obase + (((size_t)c) << 17));
    }
}

extern "C" void kernel_launch(void* const* d_in, const int* in_sizes, int n_in,
                              void* d_out, int out_size, void* d_ws, size_t ws_size,
                              hipStream_t stream)
{
    const float* inpt    = (const float*)d_in[0];
    const float* theta_w = (const float*)d_in[1];
    const float* g_w     = (const float*)d_in[2];
    const float* h_w     = (const float*)d_in[3];
    const float* h_b     = (const float*)d_in[4];
    float* out = (float*)d_out;

    char* ws = (char*)d_ws;
    float* partials = (float*)ws;                            // 4096 floats
    float* mt       = (float*)(ws + NPART * sizeof(float));  // 8 floats

    hipLaunchKernelGGL(k1_sum, dim3(NPART), dim3(256), 0, stream,
                       inpt, partials);
    hipLaunchKernelGGL(k2_mt, dim3(1), dim3(512), 0, stream,
                       partials, theta_w, mt);
    hipLaunchKernelGGL(k3_fused, dim3((BB * NSP) / 256), dim3(256), 0, stream,
                       inpt, g_w, mt, h_w, h_b, out);
}